// Round 1
// baseline (165.372 us; speedup 1.0000x reference)
//
#include <hip/hip_runtime.h>

#define COLS 16384
#define TPB  256
#define NV   (COLS / (TPB * 4))   // 16 float4 per thread
#define CAP  4096                 // candidate capacity per row

__global__ __launch_bounds__(TPB) void topk_abs_kernel(
    const float* __restrict__ x, const int* __restrict__ kp,
    float* __restrict__ out)
{
    __shared__ unsigned       ckey[CAP];
    __shared__ unsigned short ccol[CAP];
    __shared__ unsigned s_cnt;
    __shared__ int hist[256];
    __shared__ int wsum[4];
    __shared__ int s_bin, s_G, s_eq;

    const int tid  = threadIdx.x;
    const int lane = tid & 63;
    const int wid  = tid >> 6;
    const int row  = blockIdx.x;
    const int k    = kp[0];

    const float4* __restrict__ xr  = (const float4*)(x + (size_t)row * COLS);
    float4* __restrict__       or4 = (float4*)(out + (size_t)row * COLS);
    float* __restrict__        orow = out + (size_t)row * COLS;

    // ---- Pass A: streaming compaction of candidates >= T0, zero-fill output ----
    // T0 initial guess = bits(1.8f): |N(0,1)| tail prob 0.0719 -> ~1180 candidates,
    // 28 sigma inside [k=256, CAP=4096]. Binary-search fallback keeps it
    // distribution-independent (retries hit L2: row is 64 KB).
    unsigned T0 = 0x3FE66666u;           // 1.8f
    unsigned lo = 0u, hi = 0x7F800001u;  // count(>=lo) > CAP, count(>=hi) < k
    unsigned cnt = 0;

    for (int iter = 0; iter < 34; ++iter) {
        if (tid == 0) s_cnt = 0;
        __syncthreads();

        const float4 z = make_float4(0.f, 0.f, 0.f, 0.f);
        #pragma unroll
        for (int i = 0; i < NV; ++i) {
            float4 v = xr[i * TPB + tid];
            or4[i * TPB + tid] = z;                   // zero-fill (scatter comes later)
            unsigned u[4] = { __float_as_uint(v.x) & 0x7FFFFFFFu,
                              __float_as_uint(v.y) & 0x7FFFFFFFu,
                              __float_as_uint(v.z) & 0x7FFFFFFFu,
                              __float_as_uint(v.w) & 0x7FFFFFFFu };
            int colbase = (i * TPB + tid) * 4;
            #pragma unroll
            for (int e = 0; e < 4; ++e) {
                bool pred = (u[e] >= T0);
                unsigned long long m = __ballot(pred);
                int tot = __popcll(m);
                int base = 0;
                if (lane == 0) base = (int)atomicAdd(&s_cnt, (unsigned)tot);
                base = __shfl(base, 0);
                if (pred) {
                    unsigned pos = (unsigned)base +
                                   (unsigned)__popcll(m & ((1ull << lane) - 1ull));
                    if (pos < CAP) { ckey[pos] = u[e]; ccol[pos] = (unsigned short)(colbase + e); }
                }
            }
        }
        __syncthreads();              // compaction complete; ckey/ccol visible
        cnt = s_cnt;
        if (cnt >= (unsigned)k && cnt <= (unsigned)CAP) break;   // uniform
        if (cnt > (unsigned)CAP) lo = T0; else hi = T0;          // uniform update
        T0 = lo + ((hi - lo) >> 1);
        if (T0 == lo) break;          // pathological mass-tie: proceed clipped
        __syncthreads();              // everyone done reading s_cnt before reset
    }

    if (k <= 0) return;               // out already zeroed
    const unsigned cntc = cnt < (unsigned)CAP ? cnt : (unsigned)CAP;

    // ---- Pass B: exact radix-select (8 bits x 4) over candidates in LDS ----
    unsigned prefix = 0;
    int r = k;                        // rank remaining (1-based from top)
    for (int shift = 24; shift >= 0; shift -= 8) {
        hist[tid] = 0;                // TPB == 256 bins
        __syncthreads();
        for (unsigned j = tid; j < cntc; j += TPB) {
            unsigned key = ckey[j];
            if (shift == 24 || (key >> (shift + 8)) == prefix)
                atomicAdd(&hist[(key >> shift) & 0xFFu], 1);
        }
        __syncthreads();
        // suffix-cumulative count from bin 255 downward (tid order = descending bins)
        int bin = 255 - tid;
        int val = hist[bin];
        int v = val;
        #pragma unroll
        for (int d = 1; d < 64; d <<= 1) {
            int t = __shfl_up(v, d, 64);
            if (lane >= d) v += t;
        }
        if (lane == 63) wsum[wid] = v;
        __syncthreads();
        for (int w = 0; w < wid; ++w) v += wsum[w];
        // unique bin where cumulative crosses r (val>0 guaranteed there)
        if (v >= r && (v - val) < r) {
            s_bin = bin; s_G = v - val;
            if (shift == 0) s_eq = val;   // count of candidates equal to final T
        }
        __syncthreads();
        prefix = (prefix << 8) | (unsigned)s_bin;
        r -= s_G;
        __syncthreads();              // protect s_bin/s_G/hist before next pass
    }

    const unsigned T   = prefix;      // exact k-th largest |x| bits
    const int     need = r;           // # of equals-to-T to accept (lowest col first)
    const int     eq   = s_eq;        // # of candidates equal to T

    // ---- Pass C: scatter accepted values (zero-fill already done & fenced) ----
    if (eq == need) {
        // common case: accept everything >= T
        for (unsigned j = tid; j < cntc; j += TPB) {
            unsigned key = ckey[j];
            if (key >= T) orow[ccol[j]] = __uint_as_float(key);
        }
    } else {
        // rare boundary tie: rank equals by column index, accept first `need`
        for (unsigned j = tid; j < cntc; j += TPB) {
            unsigned key = ckey[j];
            if (key > T) {
                orow[ccol[j]] = __uint_as_float(key);
            } else if (key == T) {
                int rnk = 0;
                for (unsigned mjj = 0; mjj < cntc; ++mjj)
                    rnk += (ckey[mjj] == T && ccol[mjj] < ccol[j]) ? 1 : 0;
                if (rnk < need) orow[ccol[j]] = __uint_as_float(key);
            }
        }
    }
}

extern "C" void kernel_launch(void* const* d_in, const int* in_sizes, int n_in,
                              void* d_out, int out_size, void* d_ws, size_t ws_size,
                              hipStream_t stream)
{
    const float* x  = (const float*)d_in[0];
    const int*   kp = (const int*)d_in[1];
    float*       out = (float*)d_out;
    int n    = in_sizes[0];
    int rows = n / COLS;              // 4096 for the reference shape
    topk_abs_kernel<<<rows, TPB, 0, stream>>>(x, kp, out);
}

// Round 2
// 119.426 us; speedup vs baseline: 1.3847x; 1.3847x over previous
//
#include <hip/hip_runtime.h>

#define COLS 16384
#define TPB  256
#define NV   16                   // float4 per thread (16*256*4 = 16384 cols)
#define CAP  4096                 // candidate capacity per row

__global__ __launch_bounds__(TPB, 4) void topk_abs_kernel(
    const float* __restrict__ x, const int* __restrict__ kp,
    float* __restrict__ out)
{
    __shared__ unsigned       ckey[CAP];        // 16 KB
    __shared__ unsigned short ccol[CAP];        //  8 KB
    __shared__ unsigned       bmap[COLS / 32];  //  2 KB accepted-column bitmap
    __shared__ unsigned s_cnt;
    __shared__ int hist[256];
    __shared__ int wsum[4];
    __shared__ int s_bin, s_G, s_eq;

    const int tid  = threadIdx.x;
    const int lane = tid & 63;
    const int wid  = tid >> 6;
    const int row  = blockIdx.x;
    const int k    = kp[0];

    const float4* __restrict__ xr  = (const float4*)(x + (size_t)row * COLS);
    float4* __restrict__       or4 = (float4*)(out + (size_t)row * COLS);

    // ---- Load entire row into registers (64 VGPRs). No further HBM reads. ----
    float4 v[NV];
    #pragma unroll
    for (int i = 0; i < NV; ++i) v[i] = xr[i * TPB + tid];

    bmap[tid] = 0; bmap[tid + 256] = 0;   // visible after the first barrier below

    // ---- Pass A: compact candidates >= T0 into LDS (per-candidate atomic).
    // T0 = bits(1.8f): |N(0,1)| tail ~7.2% -> ~1180 candidates, 26+ sigma inside
    // [k=256, CAP=4096]. Binary-search retry re-tests REGISTERS (no re-read).
    unsigned T0 = 0x3FE66666u;           // 1.8f
    unsigned lo = 0u, hi = 0x7F800001u;
    unsigned cnt = 0;

    #pragma unroll 1
    for (int iter = 0; iter < 34; ++iter) {
        if (tid == 0) s_cnt = 0;
        __syncthreads();
        #pragma unroll
        for (int i = 0; i < NV; ++i) {
            const int cb = (i * TPB + tid) * 4;
            unsigned u0 = __float_as_uint(v[i].x) & 0x7FFFFFFFu;
            unsigned u1 = __float_as_uint(v[i].y) & 0x7FFFFFFFu;
            unsigned u2 = __float_as_uint(v[i].z) & 0x7FFFFFFFu;
            unsigned u3 = __float_as_uint(v[i].w) & 0x7FFFFFFFu;
            if (u0 >= T0) { unsigned p = atomicAdd(&s_cnt, 1u); if (p < CAP) { ckey[p] = u0; ccol[p] = (unsigned short)(cb + 0); } }
            if (u1 >= T0) { unsigned p = atomicAdd(&s_cnt, 1u); if (p < CAP) { ckey[p] = u1; ccol[p] = (unsigned short)(cb + 1); } }
            if (u2 >= T0) { unsigned p = atomicAdd(&s_cnt, 1u); if (p < CAP) { ckey[p] = u2; ccol[p] = (unsigned short)(cb + 2); } }
            if (u3 >= T0) { unsigned p = atomicAdd(&s_cnt, 1u); if (p < CAP) { ckey[p] = u3; ccol[p] = (unsigned short)(cb + 3); } }
        }
        __syncthreads();
        cnt = s_cnt;
        if (cnt >= (unsigned)k && cnt <= (unsigned)CAP) break;   // uniform
        if (cnt > (unsigned)CAP) lo = T0; else hi = T0;
        T0 = lo + ((hi - lo) >> 1);
        if (T0 == lo) break;              // pathological mass-tie: proceed clipped
        __syncthreads();                  // everyone read s_cnt before reset
    }

    if (k > 0) {
        const unsigned cntc = cnt < (unsigned)CAP ? cnt : (unsigned)CAP;

        // ---- Pass B: exact radix-select (8 bits x 4) over LDS candidates ----
        unsigned prefix = 0;
        int r = k;
        for (int shift = 24; shift >= 0; shift -= 8) {
            hist[tid] = 0;
            __syncthreads();
            for (unsigned j = tid; j < cntc; j += TPB) {
                unsigned key = ckey[j];
                if (shift == 24 || (key >> (shift + 8)) == prefix)
                    atomicAdd(&hist[(key >> shift) & 0xFFu], 1);
            }
            __syncthreads();
            int bin = 255 - tid;          // descending-bin suffix scan
            int val = hist[bin];
            int s = val;
            #pragma unroll
            for (int d = 1; d < 64; d <<= 1) {
                int t = __shfl_up(s, d, 64);
                if (lane >= d) s += t;
            }
            if (lane == 63) wsum[wid] = s;
            __syncthreads();
            for (int w = 0; w < wid; ++w) s += wsum[w];
            if (s >= r && (s - val) < r) {
                s_bin = bin; s_G = s - val;
                if (shift == 0) s_eq = val;
            }
            __syncthreads();
            prefix = (prefix << 8) | (unsigned)s_bin;
            r -= s_G;
            __syncthreads();
        }

        const unsigned T    = prefix;     // exact k-th largest |x| bits
        const int      need = r;          // equals-to-T to accept (lowest col first)
        const int      eq   = s_eq;

        // ---- Mark accepted columns in the bitmap ----
        if (eq == need) {
            for (unsigned j = tid; j < cntc; j += TPB) {
                if (ckey[j] >= T) {
                    int c = ccol[j];
                    atomicOr(&bmap[c >> 5], 1u << (c & 31));
                }
            }
        } else {
            // rare exact-tie at the boundary: rank equals by column index
            for (unsigned j = tid; j < cntc; j += TPB) {
                unsigned key = ckey[j];
                int c = ccol[j];
                if (key > T) {
                    atomicOr(&bmap[c >> 5], 1u << (c & 31));
                } else if (key == T) {
                    int rnk = 0;
                    for (unsigned m = 0; m < cntc; ++m)
                        rnk += (ckey[m] == T && ccol[m] < c) ? 1 : 0;
                    if (rnk < need) atomicOr(&bmap[c >> 5], 1u << (c & 31));
                }
            }
        }
    }
    __syncthreads();

    // ---- Pass C: compose output from registers + bitmap; write-only stream ----
    #pragma unroll
    for (int i = 0; i < NV; ++i) {
        int idx4 = i * TPB + tid;
        unsigned w = bmap[idx4 >> 3];            // 8 lanes/word -> broadcast
        unsigned b = (w >> ((idx4 & 7) * 4)) & 0xFu;
        float4 o;
        o.x = (b & 1u) ? fabsf(v[i].x) : 0.f;
        o.y = (b & 2u) ? fabsf(v[i].y) : 0.f;
        o.z = (b & 4u) ? fabsf(v[i].z) : 0.f;
        o.w = (b & 8u) ? fabsf(v[i].w) : 0.f;
        or4[idx4] = o;
    }
}

extern "C" void kernel_launch(void* const* d_in, const int* in_sizes, int n_in,
                              void* d_out, int out_size, void* d_ws, size_t ws_size,
                              hipStream_t stream)
{
    const float* x   = (const float*)d_in[0];
    const int*   kp  = (const int*)d_in[1];
    float*       out = (float*)d_out;
    int rows = in_sizes[0] / COLS;            // 4096 for the reference shape
    topk_abs_kernel<<<rows, TPB, 0, stream>>>(x, kp, out);
}